// Round 2
// baseline (2887.415 us; speedup 1.0000x reference)
//
#include <hip/hip_runtime.h>
#include <math.h>

// BayesianCTC on MI355X — round 13.
// R12 post-mortem: single-wave register scan removed LDS/barriers (bank
// conflicts 460K->0) but regressed 1333->2261us: 1 wave/SIMD exposes all
// VALU/trans/shuffle/load latency (measured 3400 cyc/step vs ~620 issue).
// R13: same math VERBATIM, fix the scheduling:
//   - 4 blocks x 512 threads: 8 independent (b,role) waves per block
//     -> 2 waves/SIMD (alpha+beta paired), latency bubbles filled.
//   - emission prefetch deepened 2->4 (4 named register sets, unroll x4).
// Predicted: scan -> 500-900us, trans-pipe issue-bound (~650-1100 cyc/step).

#define Bn    16
#define Tn    1600
#define NE    512
#define OD    2048
#define Un    200
#define Sn    401
#define NLAB  201
#define NGC   256

#define NEGINF (-INFINITY)
#define LSE_SUB_CONST_F (-2000.4586715f)        // -2001 + log(e-1)

typedef short bf8_t  __attribute__((ext_vector_type(8)));
typedef float f32x4  __attribute__((ext_vector_type(4)));

__device__ __forceinline__ unsigned short f2bf(float x) {
    unsigned int u = __float_as_uint(x);
    unsigned int r = (u + 0x7FFFu + ((u >> 16) & 1u)) >> 16;  // RNE
    return (unsigned short)r;
}
__device__ __forceinline__ void lse_merge_v(float& M, float& S, float v) {
    if (v > M) { S = S * __expf(M - v) + 1.f; M = v; }
    else       { S += __expf(v - M); }
}
__device__ __forceinline__ void lse_merge_ms(float& M, float& S, float m2, float s2) {
    if (s2 > 0.f) {
        if (m2 > M) { S = S * __expf(M - m2) + s2; M = m2; }
        else        { S += s2 * __expf(m2 - M); }
    }
}

// ------------------------------------------------------------ casts -------
__global__ __launch_bounds__(256)
void cast_hs_kernel(const float* __restrict__ src, unsigned short* __restrict__ dst, int n8) {
    int i = blockIdx.x * 256 + threadIdx.x;
    if (i >= n8) return;
    const float4* s4 = (const float4*)(src + (size_t)i * 8);
    float4 a = s4[0], b = s4[1];
    uint4 o;
    o.x = f2bf(a.x) | ((unsigned)f2bf(a.y) << 16);
    o.y = f2bf(a.z) | ((unsigned)f2bf(a.w) << 16);
    o.z = f2bf(b.x) | ((unsigned)f2bf(b.y) << 16);
    o.w = f2bf(b.z) | ((unsigned)f2bf(b.w) << 16);
    *(uint4*)(dst + (size_t)i * 8) = o;
}

// --------------------------------------------------------- gather Wg ------
__global__ __launch_bounds__(64)
void gather_kernel(const float* __restrict__ W, const float* __restrict__ bias,
                   const int* __restrict__ ys, unsigned short* __restrict__ Wgb,
                   float* __restrict__ biasg)
{
    const int b = blockIdx.x, j = blockIdx.y, tid = threadIdx.x;
    int col = -1;
    if (j == 0) col = 0;
    else if (j <= Un) { int y = ys[b * Un + j - 1]; col = (y < 0) ? 0 : y; }
    unsigned short* dst = Wgb + ((size_t)b * NGC + j) * NE;
    if (col >= 0) {
        const float* srcc = W + (size_t)col * NE;
        #pragma unroll
        for (int it = 0; it < 8; ++it) dst[tid + it * 64] = f2bf(srcc[tid + it * 64]);
    } else {
        #pragma unroll
        for (int it = 0; it < 8; ++it) dst[tid + it * 64] = 0;
    }
    if (tid == 0) biasg[b * NGC + j] = (col >= 0) ? bias[col] : 0.f;
}

// ------------------------------------------------------- main MFMA GEMM ---
#define KCH  64
#define ASTR 72

__global__ __launch_bounds__(256, 2)
void gemm_main_kernel(const unsigned short* __restrict__ hsb,
                      const unsigned short* __restrict__ Wb,
                      const float* __restrict__ bias,
                      float* __restrict__ Pm, float* __restrict__ Ps)
{
    __shared__ union {
        struct { unsigned short A[128 * ASTR]; unsigned short B[128 * ASTR]; } t;
        struct { float m[128 * 33]; float s[128 * 33]; } r;
    } sh;
    const int tid  = threadIdx.x;
    const int lane = tid & 63, w = tid >> 6;
    const int mw = w & 1, nw = w >> 1;
    const int quad = lane >> 4, lc = lane & 15;
    const int row0 = blockIdx.x * 128;
    const int c0   = blockIdx.y * 128;

    f32x4 acc[4][4];
    #pragma unroll
    for (int mi = 0; mi < 4; ++mi)
        #pragma unroll
        for (int ni = 0; ni < 4; ++ni) acc[mi][ni] = (f32x4)0.f;

    for (int kc = 0; kc < NE / KCH; ++kc) {
        __syncthreads();
        #pragma unroll
        for (int i = 0; i < 4; ++i) {
            int idx = tid + i * 256;
            int r = idx >> 3, c8 = idx & 7;
            *(uint4*)&sh.t.A[r * ASTR + c8 * 8] =
                *(const uint4*)&hsb[(size_t)(row0 + r) * NE + kc * KCH + c8 * 8];
            *(uint4*)&sh.t.B[r * ASTR + c8 * 8] =
                *(const uint4*)&Wb[(size_t)(c0 + r) * NE + kc * KCH + c8 * 8];
        }
        __syncthreads();
        #pragma unroll
        for (int ks = 0; ks < 2; ++ks) {
            bf8_t af[4], bg[4];
            #pragma unroll
            for (int mi = 0; mi < 4; ++mi)
                af[mi] = *(const bf8_t*)&sh.t.A[(mw * 64 + mi * 16 + lc) * ASTR + ks * 32 + quad * 8];
            #pragma unroll
            for (int ni = 0; ni < 4; ++ni)
                bg[ni] = *(const bf8_t*)&sh.t.B[(nw * 64 + ni * 16 + lc) * ASTR + ks * 32 + quad * 8];
            #pragma unroll
            for (int mi = 0; mi < 4; ++mi)
                #pragma unroll
                for (int ni = 0; ni < 4; ++ni)
                    acc[mi][ni] = __builtin_amdgcn_mfma_f32_16x16x32_bf16(af[mi], bg[ni], acc[mi][ni], 0, 0, 0);
        }
    }
    __syncthreads();
    float bcol[4];
    #pragma unroll
    for (int ni = 0; ni < 4; ++ni) bcol[ni] = bias[c0 + nw * 64 + ni * 16 + lc];
    #pragma unroll
    for (int mi = 0; mi < 4; ++mi)
        #pragma unroll
        for (int r = 0; r < 4; ++r) {
            float M = NEGINF, S = 0.f;
            #pragma unroll
            for (int ni = 0; ni < 4; ++ni) lse_merge_v(M, S, acc[mi][ni][r] + bcol[ni]);
            int rl = mw * 64 + mi * 16 + quad * 4 + r;
            sh.r.m[rl * 33 + nw * 16 + lc] = M;
            sh.r.s[rl * 33 + nw * 16 + lc] = S;
        }
    __syncthreads();
    if (tid < 128) {
        float M = NEGINF, S = 0.f;
        #pragma unroll 4
        for (int j = 0; j < 32; ++j) lse_merge_ms(M, S, sh.r.m[tid * 33 + j], sh.r.s[tid * 33 + j]);
        Pm[(size_t)blockIdx.y * 25600 + row0 + tid] = M;
        Ps[(size_t)blockIdx.y * 25600 + row0 + tid] = S;
    }
}

// ------------------------------------------------------------ lse reduce --
__global__ __launch_bounds__(256)
void lse_reduce_kernel(const float* __restrict__ Pm, const float* __restrict__ Ps,
                       float* __restrict__ lse)
{
    int row = blockIdx.x * 256 + threadIdx.x;
    float M = NEGINF, S = 0.f;
    #pragma unroll 4
    for (int nt = 0; nt < 16; ++nt)
        lse_merge_ms(M, S, Pm[(size_t)nt * 25600 + row], Ps[(size_t)nt * 25600 + row]);
    lse[row] = M + logf(S);
}

// ------------------------------------------------------- label MFMA GEMM --
// Output split — lpbk[row] = blank col, lpl[row][u] = label col u (u<200).
// lpl rows are 800 B -> 16 B aligned float4 reads at u = 4*lane in the scan.
__global__ __launch_bounds__(256, 2)
void gemm_label_kernel(const unsigned short* __restrict__ hsb,
                       const unsigned short* __restrict__ Wgb,
                       const float* __restrict__ biasg, const float* __restrict__ lse,
                       float* __restrict__ lpl, float* __restrict__ lpbk)
{
    __shared__ unsigned short shA[64 * ASTR];
    __shared__ unsigned short shB[128 * ASTR];
    const int tid  = threadIdx.x;
    const int lane = tid & 63, w = tid >> 6;
    const int mw = w & 1, nw = w >> 1;
    const int quad = lane >> 4, lc = lane & 15;
    const int b  = blockIdx.x / 25, mt = blockIdx.x % 25;
    const int r0 = b * Tn + mt * 64;
    const int c0 = blockIdx.y * 128;

    f32x4 acc[2][4];
    #pragma unroll
    for (int mi = 0; mi < 2; ++mi)
        #pragma unroll
        for (int ni = 0; ni < 4; ++ni) acc[mi][ni] = (f32x4)0.f;

    const unsigned short* Wgbb = Wgb + (size_t)b * NGC * NE;
    for (int kc = 0; kc < NE / KCH; ++kc) {
        __syncthreads();
        #pragma unroll
        for (int i = 0; i < 2; ++i) {
            int idx = tid + i * 256;
            int r = idx >> 3, c8 = idx & 7;
            *(uint4*)&shA[r * ASTR + c8 * 8] =
                *(const uint4*)&hsb[(size_t)(r0 + r) * NE + kc * KCH + c8 * 8];
        }
        #pragma unroll
        for (int i = 0; i < 4; ++i) {
            int idx = tid + i * 256;
            int r = idx >> 3, c8 = idx & 7;
            *(uint4*)&shB[r * ASTR + c8 * 8] =
                *(const uint4*)&Wgbb[(size_t)(c0 + r) * NE + kc * KCH + c8 * 8];
        }
        __syncthreads();
        #pragma unroll
        for (int ks = 0; ks < 2; ++ks) {
            bf8_t af[2], bg[4];
            #pragma unroll
            for (int mi = 0; mi < 2; ++mi)
                af[mi] = *(const bf8_t*)&shA[(mw * 32 + mi * 16 + lc) * ASTR + ks * 32 + quad * 8];
            #pragma unroll
            for (int ni = 0; ni < 4; ++ni)
                bg[ni] = *(const bf8_t*)&shB[(nw * 64 + ni * 16 + lc) * ASTR + ks * 32 + quad * 8];
            #pragma unroll
            for (int mi = 0; mi < 2; ++mi)
                #pragma unroll
                for (int ni = 0; ni < 4; ++ni)
                    acc[mi][ni] = __builtin_amdgcn_mfma_f32_16x16x32_bf16(af[mi], bg[ni], acc[mi][ni], 0, 0, 0);
        }
    }
    #pragma unroll
    for (int mi = 0; mi < 2; ++mi)
        #pragma unroll
        for (int r = 0; r < 4; ++r) {
            int row = r0 + mw * 32 + mi * 16 + quad * 4 + r;
            float lsv = lse[row];
            #pragma unroll
            for (int ni = 0; ni < 4; ++ni) {
                int col = c0 + nw * 64 + ni * 16 + lc;
                if (col < NLAB) {
                    float v = acc[mi][ni][r] + biasg[b * NGC + col] - lsv;
                    if (col == 0) lpbk[row] = v;
                    else          lpl[(size_t)row * Un + (col - 1)] = v;
                }
            }
        }
}

// ------------------- K2: register-resident scan, 8 waves/block ------------
__device__ __forceinline__ float lse2f(float a, float b) {
    float mx = fmaxf(a, b);
    if (isinf(mx)) return NEGINF;
    return mx + __logf(__expf(a - mx) + __expf(b - mx));
}
__device__ __forceinline__ float lse3f(float v0, float v1, float v2) {
    float mx = fmaxf(v0, fmaxf(v1, v2));
    if (isinf(mx)) return NEGINF;
    return mx + __logf(__expf(v0 - mx) + __expf(v1 - mx) + __expf(v2 - mx));
}

__global__ __launch_bounds__(512)
void scan_kernel(const float* __restrict__ lpl, const float* __restrict__ lpbk,
                 const int* __restrict__ hlens, const int* __restrict__ ys,
                 float* __restrict__ alphaU, float* __restrict__ betaP)
{
    // 4 blocks x 8 waves. Wave w: role = w>>2, b = blockIdx.x*4 + (w&3).
    // Waves are fully independent (no LDS, no __syncthreads); each CU gets
    // 2 waves/SIMD (one alpha + one beta) for latency hiding.
    const int wid  = threadIdx.x >> 6;
    const int lane = threadIdx.x & 63;
    const int role = wid >> 2;
    const int b    = blockIdx.x * 4 + (wid & 3);

    const int u0   = 4 * lane;             // first label index owned
    const int s0   = 8 * lane;             // first CTC state owned
    const int uc   = (lane < 50) ? u0 : 196;   // clamped emission base (OOB-safe)
    const bool stlane = (lane < 50);       // lanes that store aU/bP float4

    const int hlen = hlens[b];
    // olen via ballot-count (wave-uniform result)
    int olen = 0;
    #pragma unroll
    for (int c = 0; c < 4; ++c) {
        int u = lane + c * 64;
        int v = (u < Un) ? ys[b * Un + u] : -1;
        olen += (int)__popcll(__ballot(v >= 0));
    }
    // allow flags for odd states, u = u0+j  (al[4] = flag for neighbor's u0)
    bool al[5];
    #pragma unroll
    for (int j = 0; j < 5; ++j) {
        int u = u0 + j;
        bool a = false;
        if (u >= 1 && u < Un) {
            int y0 = ys[b * Un + u - 1]; if (y0 < 0) y0 = 0;
            int y1 = ys[b * Un + u];     if (y1 < 0) y1 = 0;
            a = (y0 != y1);
        }
        al[j] = a;
    }
    // state-validity masks (states >= Sn stay NEGINF forever)
    bool vm[8];
    #pragma unroll
    for (int j = 0; j < 8; ++j) vm[j] = (s0 + j < Sn);

    const float* lplb = lpl  + (size_t)b * Tn * Un;
    const float* lpbb = lpbk + (size_t)b * Tn;

    float st[8];
    #pragma unroll
    for (int j = 0; j < 8; ++j) st[j] = NEGINF;

    if (role == 0) {
        // ------------------------- alpha -------------------------
        float* aU = alphaU + (size_t)b * Tn * Un;
        if (lane == 0) { st[0] = lpbb[0]; st[1] = lplb[0]; }
        if (stlane) {
            float4 v0;
            v0.x = (lane == 0) ? lplb[0] : NEGINF;
            v0.y = NEGINF; v0.z = NEGINF; v0.w = NEGINF;
            *(float4*)&aU[u0] = v0;
        }
        auto astep = [&](int t, float eb, float4 eo) {
            float p1 = __shfl_up(st[7], 1);        // cur[s0-1] for q=0
            if (lane == 0) p1 = NEGINF;
            float ns[8];
            #pragma unroll
            for (int q = 0; q < 4; ++q) {
                float cm1 = (q == 0) ? p1 : st[2 * q - 1];
                float c2  = st[2 * q], c3 = st[2 * q + 1];
                // even state: v2 never allowed
                float nv0 = lse2f(c2, cm1);
                if (!isinf(nv0)) nv0 += eb;
                // odd state
                float a1v2 = al[q] ? cm1 : NEGINF;
                float nv1 = lse3f(c3, c2, a1v2);
                float eoq = (q == 0) ? eo.x : (q == 1) ? eo.y : (q == 2) ? eo.z : eo.w;
                if (!isinf(nv1)) nv1 += eoq;
                ns[2 * q]     = vm[2 * q]     ? nv0 : NEGINF;
                ns[2 * q + 1] = vm[2 * q + 1] ? nv1 : NEGINF;
            }
            #pragma unroll
            for (int j = 0; j < 8; ++j) st[j] = ns[j];
            if (stlane) {
                float4 v; v.x = ns[1]; v.y = ns[3]; v.z = ns[5]; v.w = ns[7];
                *(float4*)&aU[(size_t)t * Un + u0] = v;
            }
        };
        // distance-4 prefetch: sets A..D hold rows t..t+3
        float  ebA = lpbb[1];
        float4 eoA = *(const float4*)&lplb[(size_t)1 * Un + uc];
        float  ebB = lpbb[2];
        float4 eoB = *(const float4*)&lplb[(size_t)2 * Un + uc];
        float  ebC = lpbb[3];
        float4 eoC = *(const float4*)&lplb[(size_t)3 * Un + uc];
        float  ebD = lpbb[4];
        float4 eoD = *(const float4*)&lplb[(size_t)4 * Un + uc];
        int t = 1;
        for (; t + 3 < Tn; t += 4) {
            int rA = t + 4; if (rA > Tn - 1) rA = Tn - 1;
            float  nbA = lpbb[rA];
            float4 noA = *(const float4*)&lplb[(size_t)rA * Un + uc];
            astep(t, ebA, eoA);
            ebA = nbA; eoA = noA;

            int rB = t + 5; if (rB > Tn - 1) rB = Tn - 1;
            float  nbB = lpbb[rB];
            float4 noB = *(const float4*)&lplb[(size_t)rB * Un + uc];
            astep(t + 1, ebB, eoB);
            ebB = nbB; eoB = noB;

            int rC = t + 6; if (rC > Tn - 1) rC = Tn - 1;
            float  nbC = lpbb[rC];
            float4 noC = *(const float4*)&lplb[(size_t)rC * Un + uc];
            astep(t + 2, ebC, eoC);
            ebC = nbC; eoC = noC;

            int rD = t + 7; if (rD > Tn - 1) rD = Tn - 1;
            float  nbD = lpbb[rD];
            float4 noD = *(const float4*)&lplb[(size_t)rD * Un + uc];
            astep(t + 3, ebD, eoD);
            ebD = nbD; eoD = noD;
        }
        // tail (<= 3 steps), sets A.. hold the right rows already
        if (t < Tn)     astep(t,     ebA, eoA);
        if (t + 1 < Tn) astep(t + 1, ebB, eoB);
        if (t + 2 < Tn) astep(t + 2, ebC, eoC);
    } else {
        // ------------------ beta + in-scan beta_prime ------------------
        float* bP = betaP + (size_t)b * Tn * Un;
        const int olen_b = olen;
        auto bstep = [&](int tt, float eb, float4 eo) {
            float n1  = __shfl_down(st[0], 1);     // cur[s0+8]
            float n2  = __shfl_down(st[1], 1);     // cur[s0+9]
            float eo4 = __shfl_down(eo.x, 1);      // label em for u0+4
            if (lane == 63) { n1 = NEGINF; n2 = NEGINF; }
            float ns[8], bpv[4];
            #pragma unroll
            for (int q = 0; q < 4; ++q) {
                const int se = s0 + 2 * q;         // even state index
                const int u  = u0 + q;
                float c0 = st[2 * q],     c1 = st[2 * q + 1];
                float c2 = (q < 3) ? st[2 * q + 2] : n1;
                float c3 = (q < 3) ? st[2 * q + 3] : n2;
                float e0 = (q == 0) ? eo.x : (q == 1) ? eo.y : (q == 2) ? eo.z : eo.w;
                float e1 = (q == 0) ? eo.y : (q == 1) ? eo.z : (q == 2) ? eo.w : eo4;
                // even state
                float g0e = eb + c0;
                float g1e = e0 + c1;               // c1 is NEGINF when s1 invalid
                float nv0 = lse2f(g0e, g1e);
                // odd state
                float g0o = e0 + c1;
                float g1o = eb + c2;               // c2 NEGINF when s1+1 invalid
                float g2o = al[q + 1] ? (e1 + c3) : NEGINF;
                float mh = fmaxf(g1o, g2o);
                float h = NEGINF;
                if (!isinf(mh))
                    h = mh + __logf(__expf(g1o - mh) + __expf(g2o - mh));
                float nv1 = lse3f(g0o, g1o, g2o);
                if (tt == hlen - 1) {
                    nv0 = (se == 2 * olen_b || se == 2 * olen_b - 1) ? 0.f : NEGINF;
                    nv1 = (se + 1 == 2 * olen_b || se + 1 == 2 * olen_b - 1) ? 0.f : NEGINF;
                }
                ns[2 * q]     = vm[2 * q]     ? nv0 : NEGINF;
                ns[2 * q + 1] = vm[2 * q + 1] ? nv1 : NEGINF;
                // beta_prime, f64-faithful classifier (verbatim R11)
                float bp;
                if (tt >= hlen)          bp = NEGINF;
                else if (tt == hlen - 1) bp = (u == olen_b - 1) ? 0.f : NEGINF;
                else if (u >= olen_b)    bp = NEGINF;
                else if (isinf(g0o))     bp = h;
                else if (isinf(h))       bp = LSE_SUB_CONST_F;
                else {
                    float sumlog = h - g0o;
                    int k = (int)((__float_as_uint(fabsf(g0o)) >> 23) & 0xFF) - 127 - 53;
                    if (k < -53) k = -53;
                    bp = (sumlog > 709.7827f || sumlog < 0.69314718f * (float)k)
                         ? LSE_SUB_CONST_F : h;
                }
                bpv[q] = bp;
            }
            #pragma unroll
            for (int j = 0; j < 8; ++j) st[j] = ns[j];
            if (stlane) {
                float4 v; v.x = bpv[0]; v.y = bpv[1]; v.z = bpv[2]; v.w = bpv[3];
                *(float4*)&bP[(size_t)tt * Un + u0] = v;
            }
        };
        // iter tt uses emission row min(tt+1, Tn-1).
        // prologue: steps Tn-1..Tn-4 use rows Tn-1, Tn-1, Tn-2, Tn-3.
        float  ebA = lpbb[Tn - 1];
        float4 eoA = *(const float4*)&lplb[(size_t)(Tn - 1) * Un + uc];
        float  ebB = ebA;
        float4 eoB = eoA;
        float  ebC = lpbb[Tn - 2];
        float4 eoC = *(const float4*)&lplb[(size_t)(Tn - 2) * Un + uc];
        float  ebD = lpbb[Tn - 3];
        float4 eoD = *(const float4*)&lplb[(size_t)(Tn - 3) * Un + uc];
        for (int t = Tn - 1; t > 0; t -= 4) {   // 400 iterations, steps t..t-3
            int rA = t - 3; if (rA < 0) rA = 0;    // row for step t-4
            float  nbA = lpbb[rA];
            float4 noA = *(const float4*)&lplb[(size_t)rA * Un + uc];
            bstep(t, ebA, eoA);
            ebA = nbA; eoA = noA;

            int rB = t - 4; if (rB < 0) rB = 0;    // row for step t-5
            float  nbB = lpbb[rB];
            float4 noB = *(const float4*)&lplb[(size_t)rB * Un + uc];
            bstep(t - 1, ebB, eoB);
            ebB = nbB; eoB = noB;

            int rC = t - 5; if (rC < 0) rC = 0;    // row for step t-6
            float  nbC = lpbb[rC];
            float4 noC = *(const float4*)&lplb[(size_t)rC * Un + uc];
            bstep(t - 2, ebC, eoC);
            ebC = nbC; eoC = noC;

            int rD = t - 6; if (rD < 0) rD = 0;    // row for step t-7
            float  nbD = lpbb[rD];
            float4 noD = *(const float4*)&lplb[(size_t)rD * Un + uc];
            bstep(t - 3, ebD, eoD);
            ebD = nbD; eoD = noD;
        }
    }
}

// --------------------- K3: t-parallel f32 loss ----------------------------
#define TCH 8
#define TPC (Tn / TCH)

__global__ __launch_bounds__(256)
void loss_partial_kernel(const int* __restrict__ hlens,
                         const float* __restrict__ alphaU, const float* __restrict__ betaP,
                         float* __restrict__ pm, float* __restrict__ ps)
{
    const int b = blockIdx.x, ch = blockIdx.y, tid = threadIdx.x;
    const int hlen = hlens[b];
    const float risk_c = 0.1f / (float)hlen;
    float m = NEGINF, s = 0.f;
    if (tid < Un) {
        const float* aU = alphaU + (size_t)b * Tn * Un + tid;
        const float* bP = betaP  + (size_t)b * Tn * Un + tid;
        const int t0 = ch * TPC, t1 = t0 + TPC;
        for (int t = t0; t < t1; ++t) {
            float st = aU[(size_t)t * Un] + bP[(size_t)t * Un] + (float)(t + 1) * risk_c;
            if (!isinf(st)) lse_merge_v(m, s, st);
        }
    }
    pm[((size_t)b * TCH + ch) * 256 + tid] = m;
    ps[((size_t)b * TCH + ch) * 256 + tid] = s;
}

__global__ __launch_bounds__(256)
void loss_combine_kernel(const float* __restrict__ pm, const float* __restrict__ ps,
                         const int* __restrict__ hlens, const int* __restrict__ ys,
                         float* __restrict__ lossb)
{
    const int b = blockIdx.x, tid = threadIdx.x;
    __shared__ float lu[Un];
    __shared__ int sh_olen;
    if (tid == 0) {
        int o = 0;
        for (int u = 0; u < Un; u++) if (ys[b * Un + u] >= 0) o++;
        sh_olen = o;
    }
    __syncthreads();
    if (tid < Un) {
        float M = NEGINF, S = 0.f;
        #pragma unroll
        for (int c = 0; c < TCH; ++c)
            lse_merge_ms(M, S, pm[((size_t)b * TCH + c) * 256 + tid],
                               ps[((size_t)b * TCH + c) * 256 + tid]);
        lu[tid] = (S == 0.f) ? NEGINF : M + __logf(S);
    }
    __syncthreads();
    if (tid == 0) {
        int cnt = 0;
        for (int u = 0; u < Un; u++) if (!isinf(lu[u])) cnt++;
        int last = cnt - 1; if (last < 0) last = 0;
        float lf = lu[last];
        if (hlens[b] < sh_olen) lf = 0.f;
        lossb[b] = lf;
    }
}

// ---------------------------------------------------------------- K4 ------
__global__ void finalize_kernel(const float* __restrict__ lossb, float* __restrict__ out) {
    if (threadIdx.x == 0 && blockIdx.x == 0) {
        float ssum = 0.f;
        for (int i = 0; i < Bn; i++) ssum += lossb[i];
        out[0] = -ssum / (float)Bn;
    }
}

// ------------------------------------------------------------- launch -----
extern "C" void kernel_launch(void* const* d_in, const int* in_sizes, int n_in,
                              void* d_out, int out_size, void* d_ws, size_t ws_size,
                              hipStream_t stream) {
    const float* hs    = (const float*)d_in[0];
    const float* W     = (const float*)d_in[1];
    const float* bias  = (const float*)d_in[2];
    const int*   hlens = (const int*)d_in[3];
    const int*   ys    = (const int*)d_in[4];
    float* out = (float*)d_out;

    // ---- workspace (~97.9 MB) ----
    char* p = (char*)d_ws;
    float* lpl    = (float*)p;  p += (size_t)25600 * Un * 4;          // 20.48 MB
    float* lpbk   = (float*)p;  p += (size_t)25600 * 4;               // 0.10 MB
    float* alphaU = (float*)p;  p += (size_t)Bn * Tn * Un * 4;        // 20.48 MB
    float* betaP  = (float*)p;  p += (size_t)Bn * Tn * Un * 4;        // 20.48 MB
    unsigned short* hsb = (unsigned short*)p; p += (size_t)25600 * NE * 2;    // 26.2 MB
    unsigned short* Wb  = (unsigned short*)p; p += (size_t)OD * NE * 2;       // 2.1 MB
    unsigned short* Wgb = (unsigned short*)p; p += (size_t)Bn * NGC * NE * 2; // 4.2 MB
    float* Pm    = (float*)p;   p += (size_t)16 * 25600 * 4;          // 1.64 MB
    float* Ps    = (float*)p;   p += (size_t)16 * 25600 * 4;          // 1.64 MB
    float* lse   = (float*)p;   p += (size_t)25600 * 4;               // 0.10 MB
    float* biasg = (float*)p;   p += (size_t)Bn * NGC * 4;            // 16 KB
    float* pm    = (float*)p;   p += (size_t)Bn * TCH * 256 * 4;
    float* ps    = (float*)p;   p += (size_t)Bn * TCH * 256 * 4;
    float* lossb = (float*)p;   p += 256;

    hipLaunchKernelGGL(cast_hs_kernel, dim3(6400), dim3(256), 0, stream,
                       hs, hsb, 25600 * NE / 8);
    hipLaunchKernelGGL(cast_hs_kernel, dim3(512), dim3(256), 0, stream,
                       W, Wb, OD * NE / 8);
    hipLaunchKernelGGL(gather_kernel, dim3(Bn, NGC), dim3(64), 0, stream,
                       W, bias, ys, Wgb, biasg);
    hipLaunchKernelGGL(gemm_main_kernel, dim3(200, 16), dim3(256), 0, stream,
                       hsb, Wb, bias, Pm, Ps);
    hipLaunchKernelGGL(lse_reduce_kernel, dim3(100), dim3(256), 0, stream,
                       Pm, Ps, lse);
    hipLaunchKernelGGL(gemm_label_kernel, dim3(400, 2), dim3(256), 0, stream,
                       hsb, Wgb, biasg, lse, lpl, lpbk);
    hipLaunchKernelGGL(scan_kernel, dim3(4), dim3(512), 0, stream,
                       lpl, lpbk, hlens, ys, alphaU, betaP);
    hipLaunchKernelGGL(loss_partial_kernel, dim3(Bn, TCH), dim3(256), 0, stream,
                       hlens, alphaU, betaP, pm, ps);
    hipLaunchKernelGGL(loss_combine_kernel, dim3(Bn), dim3(256), 0, stream,
                       pm, ps, hlens, ys, lossb);
    hipLaunchKernelGGL(finalize_kernel, dim3(1), dim3(64), 0, stream, lossb, out);
}

// Round 3
// 1234.304 us; speedup vs baseline: 2.3393x; 2.3393x over previous
//
#include <hip/hip_runtime.h>
#include <math.h>

// BayesianCTC on MI355X — round 14.
// R12/R13 post-mortem: scan wall = ONE wave's serial dependent chain; TLP
// (R13) cannot shorten it (VALUBusy/CU rose to ~76%, wall unchanged). The
// chain is memory-latency-bound: __syncthreads drains vmcnt(0) every step
// (compiler emits full waitcnt before s_barrier), so emission prefetch dies
// at each barrier and every step pays the L3 round trip.
// R14: back to the proven R11 4-wave LDS ping-pong structure (anchor 1333us),
// with three changes:
//  - per-step barrier = asm "s_waitcnt lgkmcnt(0)" + raw s_barrier builtin
//    (+ sched_barrier(0)): LDS-only ordering, global loads stay in flight
//    across barriers (m201/T4 pattern) -> depth-4 emission prefetch works.
//  - only u* = olen-1 is needed downstream (last = olen-1 whenever
//    hlen >= olen, guaranteed here): scan stores ONE dword/step/role
//    (ast/bst), alphaU/betaP (41 MB) + loss_partial eliminated; tiny loss
//    kernel reproduces the old chunked merge order bit-for-bit.
//  - allow flags computed in registers (no LDS table).
// All state-update math verbatim R11/R12 (same lse ordering, same f32
// collapse classifier).

#define Bn    16
#define Tn    1600
#define NE    512
#define OD    2048
#define Un    200
#define Sn    401
#define NLAB  201
#define NGC   256

#define NEGINF (-INFINITY)
#define LSE_SUB_CONST_F (-2000.4586715f)        // -2001 + log(e-1)

typedef short bf8_t  __attribute__((ext_vector_type(8)));
typedef float f32x4  __attribute__((ext_vector_type(4)));

__device__ __forceinline__ unsigned short f2bf(float x) {
    unsigned int u = __float_as_uint(x);
    unsigned int r = (u + 0x7FFFu + ((u >> 16) & 1u)) >> 16;  // RNE
    return (unsigned short)r;
}
__device__ __forceinline__ void lse_merge_v(float& M, float& S, float v) {
    if (v > M) { S = S * __expf(M - v) + 1.f; M = v; }
    else       { S += __expf(v - M); }
}
__device__ __forceinline__ void lse_merge_ms(float& M, float& S, float m2, float s2) {
    if (s2 > 0.f) {
        if (m2 > M) { S = S * __expf(M - m2) + s2; M = m2; }
        else        { S += s2 * __expf(m2 - M); }
    }
}

// ------------------------------------------------------------ casts -------
__global__ __launch_bounds__(256)
void cast_hs_kernel(const float* __restrict__ src, unsigned short* __restrict__ dst, int n8) {
    int i = blockIdx.x * 256 + threadIdx.x;
    if (i >= n8) return;
    const float4* s4 = (const float4*)(src + (size_t)i * 8);
    float4 a = s4[0], b = s4[1];
    uint4 o;
    o.x = f2bf(a.x) | ((unsigned)f2bf(a.y) << 16);
    o.y = f2bf(a.z) | ((unsigned)f2bf(a.w) << 16);
    o.z = f2bf(b.x) | ((unsigned)f2bf(b.y) << 16);
    o.w = f2bf(b.z) | ((unsigned)f2bf(b.w) << 16);
    *(uint4*)(dst + (size_t)i * 8) = o;
}

// --------------------------------------------------------- gather Wg ------
__global__ __launch_bounds__(64)
void gather_kernel(const float* __restrict__ W, const float* __restrict__ bias,
                   const int* __restrict__ ys, unsigned short* __restrict__ Wgb,
                   float* __restrict__ biasg)
{
    const int b = blockIdx.x, j = blockIdx.y, tid = threadIdx.x;
    int col = -1;
    if (j == 0) col = 0;
    else if (j <= Un) { int y = ys[b * Un + j - 1]; col = (y < 0) ? 0 : y; }
    unsigned short* dst = Wgb + ((size_t)b * NGC + j) * NE;
    if (col >= 0) {
        const float* srcc = W + (size_t)col * NE;
        #pragma unroll
        for (int it = 0; it < 8; ++it) dst[tid + it * 64] = f2bf(srcc[tid + it * 64]);
    } else {
        #pragma unroll
        for (int it = 0; it < 8; ++it) dst[tid + it * 64] = 0;
    }
    if (tid == 0) biasg[b * NGC + j] = (col >= 0) ? bias[col] : 0.f;
}

// ------------------------------------------------------- main MFMA GEMM ---
#define KCH  64
#define ASTR 72

__global__ __launch_bounds__(256, 2)
void gemm_main_kernel(const unsigned short* __restrict__ hsb,
                      const unsigned short* __restrict__ Wb,
                      const float* __restrict__ bias,
                      float* __restrict__ Pm, float* __restrict__ Ps)
{
    __shared__ union {
        struct { unsigned short A[128 * ASTR]; unsigned short B[128 * ASTR]; } t;
        struct { float m[128 * 33]; float s[128 * 33]; } r;
    } sh;
    const int tid  = threadIdx.x;
    const int lane = tid & 63, w = tid >> 6;
    const int mw = w & 1, nw = w >> 1;
    const int quad = lane >> 4, lc = lane & 15;
    const int row0 = blockIdx.x * 128;
    const int c0   = blockIdx.y * 128;

    f32x4 acc[4][4];
    #pragma unroll
    for (int mi = 0; mi < 4; ++mi)
        #pragma unroll
        for (int ni = 0; ni < 4; ++ni) acc[mi][ni] = (f32x4)0.f;

    for (int kc = 0; kc < NE / KCH; ++kc) {
        __syncthreads();
        #pragma unroll
        for (int i = 0; i < 4; ++i) {
            int idx = tid + i * 256;
            int r = idx >> 3, c8 = idx & 7;
            *(uint4*)&sh.t.A[r * ASTR + c8 * 8] =
                *(const uint4*)&hsb[(size_t)(row0 + r) * NE + kc * KCH + c8 * 8];
            *(uint4*)&sh.t.B[r * ASTR + c8 * 8] =
                *(const uint4*)&Wb[(size_t)(c0 + r) * NE + kc * KCH + c8 * 8];
        }
        __syncthreads();
        #pragma unroll
        for (int ks = 0; ks < 2; ++ks) {
            bf8_t af[4], bg[4];
            #pragma unroll
            for (int mi = 0; mi < 4; ++mi)
                af[mi] = *(const bf8_t*)&sh.t.A[(mw * 64 + mi * 16 + lc) * ASTR + ks * 32 + quad * 8];
            #pragma unroll
            for (int ni = 0; ni < 4; ++ni)
                bg[ni] = *(const bf8_t*)&sh.t.B[(nw * 64 + ni * 16 + lc) * ASTR + ks * 32 + quad * 8];
            #pragma unroll
            for (int mi = 0; mi < 4; ++mi)
                #pragma unroll
                for (int ni = 0; ni < 4; ++ni)
                    acc[mi][ni] = __builtin_amdgcn_mfma_f32_16x16x32_bf16(af[mi], bg[ni], acc[mi][ni], 0, 0, 0);
        }
    }
    __syncthreads();
    float bcol[4];
    #pragma unroll
    for (int ni = 0; ni < 4; ++ni) bcol[ni] = bias[c0 + nw * 64 + ni * 16 + lc];
    #pragma unroll
    for (int mi = 0; mi < 4; ++mi)
        #pragma unroll
        for (int r = 0; r < 4; ++r) {
            float M = NEGINF, S = 0.f;
            #pragma unroll
            for (int ni = 0; ni < 4; ++ni) lse_merge_v(M, S, acc[mi][ni][r] + bcol[ni]);
            int rl = mw * 64 + mi * 16 + quad * 4 + r;
            sh.r.m[rl * 33 + nw * 16 + lc] = M;
            sh.r.s[rl * 33 + nw * 16 + lc] = S;
        }
    __syncthreads();
    if (tid < 128) {
        float M = NEGINF, S = 0.f;
        #pragma unroll 4
        for (int j = 0; j < 32; ++j) lse_merge_ms(M, S, sh.r.m[tid * 33 + j], sh.r.s[tid * 33 + j]);
        Pm[(size_t)blockIdx.y * 25600 + row0 + tid] = M;
        Ps[(size_t)blockIdx.y * 25600 + row0 + tid] = S;
    }
}

// ------------------------------------------------------------ lse reduce --
__global__ __launch_bounds__(256)
void lse_reduce_kernel(const float* __restrict__ Pm, const float* __restrict__ Ps,
                       float* __restrict__ lse)
{
    int row = blockIdx.x * 256 + threadIdx.x;
    float M = NEGINF, S = 0.f;
    #pragma unroll 4
    for (int nt = 0; nt < 16; ++nt)
        lse_merge_ms(M, S, Pm[(size_t)nt * 25600 + row], Ps[(size_t)nt * 25600 + row]);
    lse[row] = M + logf(S);
}

// ------------------------------------------------------- label MFMA GEMM --
// Output split — lpbk[row] = blank col, lpl[row][u] = label col u (u<200).
__global__ __launch_bounds__(256, 2)
void gemm_label_kernel(const unsigned short* __restrict__ hsb,
                       const unsigned short* __restrict__ Wgb,
                       const float* __restrict__ biasg, const float* __restrict__ lse,
                       float* __restrict__ lpl, float* __restrict__ lpbk)
{
    __shared__ unsigned short shA[64 * ASTR];
    __shared__ unsigned short shB[128 * ASTR];
    const int tid  = threadIdx.x;
    const int lane = tid & 63, w = tid >> 6;
    const int mw = w & 1, nw = w >> 1;
    const int quad = lane >> 4, lc = lane & 15;
    const int b  = blockIdx.x / 25, mt = blockIdx.x % 25;
    const int r0 = b * Tn + mt * 64;
    const int c0 = blockIdx.y * 128;

    f32x4 acc[2][4];
    #pragma unroll
    for (int mi = 0; mi < 2; ++mi)
        #pragma unroll
        for (int ni = 0; ni < 4; ++ni) acc[mi][ni] = (f32x4)0.f;

    const unsigned short* Wgbb = Wgb + (size_t)b * NGC * NE;
    for (int kc = 0; kc < NE / KCH; ++kc) {
        __syncthreads();
        #pragma unroll
        for (int i = 0; i < 2; ++i) {
            int idx = tid + i * 256;
            int r = idx >> 3, c8 = idx & 7;
            *(uint4*)&shA[r * ASTR + c8 * 8] =
                *(const uint4*)&hsb[(size_t)(r0 + r) * NE + kc * KCH + c8 * 8];
        }
        #pragma unroll
        for (int i = 0; i < 4; ++i) {
            int idx = tid + i * 256;
            int r = idx >> 3, c8 = idx & 7;
            *(uint4*)&shB[r * ASTR + c8 * 8] =
                *(const uint4*)&Wgbb[(size_t)(c0 + r) * NE + kc * KCH + c8 * 8];
        }
        __syncthreads();
        #pragma unroll
        for (int ks = 0; ks < 2; ++ks) {
            bf8_t af[2], bg[4];
            #pragma unroll
            for (int mi = 0; mi < 2; ++mi)
                af[mi] = *(const bf8_t*)&shA[(mw * 32 + mi * 16 + lc) * ASTR + ks * 32 + quad * 8];
            #pragma unroll
            for (int ni = 0; ni < 4; ++ni)
                bg[ni] = *(const bf8_t*)&shB[(nw * 64 + ni * 16 + lc) * ASTR + ks * 32 + quad * 8];
            #pragma unroll
            for (int mi = 0; mi < 2; ++mi)
                #pragma unroll
                for (int ni = 0; ni < 4; ++ni)
                    acc[mi][ni] = __builtin_amdgcn_mfma_f32_16x16x32_bf16(af[mi], bg[ni], acc[mi][ni], 0, 0, 0);
        }
    }
    #pragma unroll
    for (int mi = 0; mi < 2; ++mi)
        #pragma unroll
        for (int r = 0; r < 4; ++r) {
            int row = r0 + mw * 32 + mi * 16 + quad * 4 + r;
            float lsv = lse[row];
            #pragma unroll
            for (int ni = 0; ni < 4; ++ni) {
                int col = c0 + nw * 64 + ni * 16 + lc;
                if (col < NLAB) {
                    float v = acc[mi][ni][r] + biasg[b * NGC + col] - lsv;
                    if (col == 0) lpbk[row] = v;
                    else          lpl[(size_t)row * Un + (col - 1)] = v;
                }
            }
        }
}

// ------------------- K2: LDS ping-pong scan, light barrier ----------------
#define IDX(s) ((s) + 2)          // buf index for state s; pads [0,1],[403..407]

__device__ __forceinline__ float lse2f(float a, float b) {
    float mx = fmaxf(a, b);
    if (isinf(mx)) return NEGINF;
    return mx + __logf(__expf(a - mx) + __expf(b - mx));
}
__device__ __forceinline__ float lse3f(float v0, float v1, float v2) {
    float mx = fmaxf(v0, fmaxf(v1, v2));
    if (isinf(mx)) return NEGINF;
    return mx + __logf(__expf(v0 - mx) + __expf(v1 - mx) + __expf(v2 - mx));
}

// LDS-only barrier: ds writes visible, global loads stay in flight (vmcnt
// NOT drained — this is the whole point; __syncthreads would drain it).
#define STEP_BAR() do { \
    asm volatile("s_waitcnt lgkmcnt(0)" ::: "memory"); \
    __builtin_amdgcn_s_barrier(); \
    __builtin_amdgcn_sched_barrier(0); \
} while (0)

__global__ __launch_bounds__(256)
void scan_kernel(const float* __restrict__ lpl, const float* __restrict__ lpbk,
                 const int* __restrict__ hlens, const int* __restrict__ ys,
                 float* __restrict__ ast, float* __restrict__ bst)
{
    __shared__ float buf[2][408];
    __shared__ int   sh_olen, sh_hlen;

    const int b    = blockIdx.x & (Bn - 1);
    const int role = blockIdx.x >> 4;
    const int tid  = threadIdx.x;        // thread i owns states 2i, 2i+1

    if (tid == 0) {
        int o = 0;
        for (int u = 0; u < Un; u++) if (ys[b * Un + u] >= 0) o++;
        sh_olen = o;
        sh_hlen = hlens[b];
    }
    for (int idx = tid; idx < 408; idx += 256) {
        buf[0][idx] = NEGINF;
        buf[1][idx] = NEGINF;
    }
    // allow flags in registers (loop-invariant)
    bool a1allow = false;                // allow for odd state s1 (u = tid)
    if (tid >= 1 && tid < Un) {
        int y0 = ys[b * Un + tid - 1]; if (y0 < 0) y0 = 0;
        int y1 = ys[b * Un + tid];     if (y1 < 0) y1 = 0;
        a1allow = (y0 != y1);
    }
    bool a2allow = false;                // allow for odd state s1+2 (u = tid+1)
    if (tid + 1 >= 1 && tid + 1 < Un) {
        int y0 = ys[b * Un + tid];     if (y0 < 0) y0 = 0;
        int y1 = ys[b * Un + tid + 1]; if (y1 < 0) y1 = 0;
        a2allow = (y0 != y1);
    }
    __syncthreads();

    const float* lplb = lpl + (size_t)b * Tn * Un;
    const float* lpbb = lpbk + (size_t)b * Tn;
    const int s0 = 2 * tid, s1 = 2 * tid + 1;
    const bool v0ok = (s0 < Sn);         // tid <= 200
    const bool v1ok = (s1 < Sn);         // tid < 200
    const int  olen = sh_olen, hlen = sh_hlen;
    const int  ustar = olen - 1;

    if (role == 0) {
        // ------------------------- alpha -------------------------
        float* as = ast + (size_t)b * Tn;
        if (tid == 0) { buf[0][IDX(0)] = lpbb[0]; buf[0][IDX(1)] = lplb[0]; }
        if (tid == ustar) as[0] = (tid == 0) ? lplb[0] : NEGINF;
        __syncthreads();

        #define ASTEP(T, EB, EO) do { \
            const float* cur = buf[((T) - 1) & 1]; \
            float* nxt = buf[(T) & 1]; \
            if (v0ok) { \
                float c1 = cur[IDX(s0) - 1]; \
                float c2 = cur[IDX(s0)], c3 = cur[IDX(s1)]; \
                float nv0 = lse2f(c2, c1); \
                if (!isinf(nv0)) nv0 += (EB); \
                nxt[IDX(s0)] = nv0; \
                if (v1ok) { \
                    float a1v2 = a1allow ? c1 : NEGINF; \
                    float nv1 = lse3f(c3, c2, a1v2); \
                    if (!isinf(nv1)) nv1 += (EO); \
                    nxt[IDX(s1)] = nv1; \
                    if (tid == ustar) as[T] = nv1; \
                } \
            } \
            STEP_BAR(); \
        } while (0)

        // depth-4 prefetch: sets A..D hold emission rows t..t+3
        float ebA = lpbb[1], ebB = lpbb[2], ebC = lpbb[3], ebD = lpbb[4];
        float eoA = (tid < Un) ? lplb[(size_t)1 * Un + tid] : 0.f;
        float eoB = (tid < Un) ? lplb[(size_t)2 * Un + tid] : 0.f;
        float eoC = (tid < Un) ? lplb[(size_t)3 * Un + tid] : 0.f;
        float eoD = (tid < Un) ? lplb[(size_t)4 * Un + tid] : 0.f;
        int t = 1;
        for (; t + 3 < Tn; t += 4) {       // t = 1..1593, covers steps to 1596
            int rA = t + 4; if (rA > Tn - 1) rA = Tn - 1;
            float nbA = lpbb[rA];
            float noA = (tid < Un) ? lplb[(size_t)rA * Un + tid] : 0.f;
            ASTEP(t, ebA, eoA); ebA = nbA; eoA = noA;

            int rB = t + 5; if (rB > Tn - 1) rB = Tn - 1;
            float nbB = lpbb[rB];
            float noB = (tid < Un) ? lplb[(size_t)rB * Un + tid] : 0.f;
            ASTEP(t + 1, ebB, eoB); ebB = nbB; eoB = noB;

            int rC = t + 6; if (rC > Tn - 1) rC = Tn - 1;
            float nbC = lpbb[rC];
            float noC = (tid < Un) ? lplb[(size_t)rC * Un + tid] : 0.f;
            ASTEP(t + 2, ebC, eoC); ebC = nbC; eoC = noC;

            int rD = t + 7; if (rD > Tn - 1) rD = Tn - 1;
            float nbD = lpbb[rD];
            float noD = (tid < Un) ? lplb[(size_t)rD * Un + tid] : 0.f;
            ASTEP(t + 3, ebD, eoD); ebD = nbD; eoD = noD;
        }
        // tail: t = 1597, 1598, 1599 (sets A,B,C already hold those rows)
        if (t < Tn)     ASTEP(t,     ebA, eoA);
        if (t + 1 < Tn) ASTEP(t + 1, ebB, eoB);
        if (t + 2 < Tn) ASTEP(t + 2, ebC, eoC);
        #undef ASTEP
    } else {
        // ------------------ beta + in-scan beta_prime ------------------
        float* bs = bst + (size_t)b * Tn;
        __syncthreads();                   // match alpha's extra barrier? not
        // needed (independent block), but keeps LDS init ordering obvious.

        #define BSTEP(T, EB, E0, E1) do { \
            const int it = (Tn - 1 - (T)) & 1; \
            const float* cur = buf[it]; \
            float* nxt = buf[it ^ 1]; \
            if (v0ok) { \
                float c0 = cur[IDX(s0)],     c1 = cur[IDX(s0) + 1]; \
                float c2 = cur[IDX(s0) + 2], c3 = cur[IDX(s0) + 3]; \
                float g0e = (EB) + c0; \
                float g1e = (E0) + c1; \
                float nv0 = lse2f(g0e, g1e); \
                float g0o = (E0) + c1; \
                float g1o = (EB) + c2; \
                float g2o = a2allow ? ((E1) + c3) : NEGINF; \
                float mh = fmaxf(g1o, g2o); \
                float h = NEGINF; \
                if (!isinf(mh)) \
                    h = mh + __logf(__expf(g1o - mh) + __expf(g2o - mh)); \
                float nv1 = v1ok ? lse3f(g0o, g1o, g2o) : NEGINF; \
                if ((T) == hlen - 1) { \
                    nv0 = (s0 == 2 * olen || s0 == 2 * olen - 1) ? 0.f : NEGINF; \
                    nv1 = (s1 == 2 * olen || s1 == 2 * olen - 1) ? 0.f : NEGINF; \
                } \
                nxt[IDX(s0)] = nv0; \
                if (v1ok) { \
                    nxt[IDX(s1)] = nv1; \
                    if (tid == ustar) { \
                        float bp; \
                        if ((T) >= hlen)          bp = NEGINF; \
                        else if ((T) == hlen - 1) bp = 0.f; /* tid==olen-1 */ \
                        else if (isinf(g0o))      bp = h; \
                        else if (isinf(h))        bp = LSE_SUB_CONST_F; \
                        else { \
                            float sumlog = h - g0o; \
                            int k = (int)((__float_as_uint(fabsf(g0o)) >> 23) & 0xFF) - 127 - 53; \
                            if (k < -53) k = -53; \
                            bp = (sumlog > 709.7827f || sumlog < 0.69314718f * (float)k) \
                                 ? LSE_SUB_CONST_F : h; \
                        } \
                        bs[T] = bp; \
                    } \
                } \
            } \
            STEP_BAR(); \
        } while (0)

        // step T uses emission row min(T+1, Tn-1).
        // prologue: steps 1599,1598,1597,1596 -> rows 1599,1599,1598,1597.
        float ebA = lpbb[Tn - 1];
        float e0A = (tid < Un)     ? lplb[(size_t)(Tn - 1) * Un + tid]     : 0.f;
        float e1A = (tid + 1 < Un) ? lplb[(size_t)(Tn - 1) * Un + tid + 1] : 0.f;
        float ebB = ebA, e0B = e0A, e1B = e1A;
        float ebC = lpbb[Tn - 2];
        float e0C = (tid < Un)     ? lplb[(size_t)(Tn - 2) * Un + tid]     : 0.f;
        float e1C = (tid + 1 < Un) ? lplb[(size_t)(Tn - 2) * Un + tid + 1] : 0.f;
        float ebD = lpbb[Tn - 3];
        float e0D = (tid < Un)     ? lplb[(size_t)(Tn - 3) * Un + tid]     : 0.f;
        float e1D = (tid + 1 < Un) ? lplb[(size_t)(Tn - 3) * Un + tid + 1] : 0.f;
        for (int t = Tn - 1; t > 0; t -= 4) {   // 400 iters, steps t..t-3
            int rA = t - 3; if (rA < 0) rA = 0;     // row for step t-4
            float nbA = lpbb[rA];
            float n0A = (tid < Un)     ? lplb[(size_t)rA * Un + tid]     : 0.f;
            float n1A = (tid + 1 < Un) ? lplb[(size_t)rA * Un + tid + 1] : 0.f;
            BSTEP(t, ebA, e0A, e1A); ebA = nbA; e0A = n0A; e1A = n1A;

            int rB = t - 4; if (rB < 0) rB = 0;     // row for step t-5
            float nbB = lpbb[rB];
            float n0B = (tid < Un)     ? lplb[(size_t)rB * Un + tid]     : 0.f;
            float n1B = (tid + 1 < Un) ? lplb[(size_t)rB * Un + tid + 1] : 0.f;
            BSTEP(t - 1, ebB, e0B, e1B); ebB = nbB; e0B = n0B; e1B = n1B;

            int rC = t - 5; if (rC < 0) rC = 0;     // row for step t-6
            float nbC = lpbb[rC];
            float n0C = (tid < Un)     ? lplb[(size_t)rC * Un + tid]     : 0.f;
            float n1C = (tid + 1 < Un) ? lplb[(size_t)rC * Un + tid + 1] : 0.f;
            BSTEP(t - 2, ebC, e0C, e1C); ebC = nbC; e0C = n0C; e1C = n1C;

            int rD = t - 6; if (rD < 0) rD = 0;     // row for step t-7
            float nbD = lpbb[rD];
            float n0D = (tid < Un)     ? lplb[(size_t)rD * Un + tid]     : 0.f;
            float n1D = (tid + 1 < Un) ? lplb[(size_t)rD * Un + tid + 1] : 0.f;
            BSTEP(t - 3, ebD, e0D, e1D); ebD = nbD; e0D = n0D; e1D = n1D;
        }
        #undef BSTEP
    }
}

// --------------------- K3: loss at u* only --------------------------------
// Reproduces the old loss_partial (8 chunks of 200, serial) + combine
// (serial over chunks) arithmetic exactly, for u = olen-1 only.
#define TCH 8
#define TPC (Tn / TCH)

__global__ __launch_bounds__(64)
void loss_kernel(const int* __restrict__ hlens, const int* __restrict__ ys,
                 const float* __restrict__ ast, const float* __restrict__ bst,
                 float* __restrict__ lossb)
{
    const int b = blockIdx.x, tid = threadIdx.x;
    __shared__ float sm[TCH], ss[TCH];
    __shared__ int sh_olen;
    if (tid == 0) {
        int o = 0;
        for (int u = 0; u < Un; u++) if (ys[b * Un + u] >= 0) o++;
        sh_olen = o;
    }
    __syncthreads();
    const int hlen = hlens[b];
    const float risk_c = 0.1f / (float)hlen;
    if (tid < TCH) {
        float m = NEGINF, s = 0.f;
        const float* as = ast + (size_t)b * Tn;
        const float* bs = bst + (size_t)b * Tn;
        const int t0 = tid * TPC, t1 = t0 + TPC;
        for (int t = t0; t < t1; ++t) {
            float v = as[t] + bs[t] + (float)(t + 1) * risk_c;
            if (!isinf(v)) lse_merge_v(m, s, v);
        }
        sm[tid] = m; ss[tid] = s;
    }
    __syncthreads();
    if (tid == 0) {
        float M = NEGINF, S = 0.f;
        #pragma unroll
        for (int c = 0; c < TCH; ++c) lse_merge_ms(M, S, sm[c], ss[c]);
        float lf = (S == 0.f) ? NEGINF : M + __logf(S);
        if (hlen < sh_olen) lf = 0.f;
        lossb[b] = lf;
    }
}

// ---------------------------------------------------------------- K4 ------
__global__ void finalize_kernel(const float* __restrict__ lossb, float* __restrict__ out) {
    if (threadIdx.x == 0 && blockIdx.x == 0) {
        float ssum = 0.f;
        for (int i = 0; i < Bn; i++) ssum += lossb[i];
        out[0] = -ssum / (float)Bn;
    }
}

// ------------------------------------------------------------- launch -----
extern "C" void kernel_launch(void* const* d_in, const int* in_sizes, int n_in,
                              void* d_out, int out_size, void* d_ws, size_t ws_size,
                              hipStream_t stream) {
    const float* hs    = (const float*)d_in[0];
    const float* W     = (const float*)d_in[1];
    const float* bias  = (const float*)d_in[2];
    const int*   hlens = (const int*)d_in[3];
    const int*   ys    = (const int*)d_in[4];
    float* out = (float*)d_out;

    // ---- workspace (~57 MB) ----
    char* p = (char*)d_ws;
    float* lpl    = (float*)p;  p += (size_t)25600 * Un * 4;          // 20.48 MB
    float* lpbk   = (float*)p;  p += (size_t)25600 * 4;               // 0.10 MB
    unsigned short* hsb = (unsigned short*)p; p += (size_t)25600 * NE * 2;    // 26.2 MB
    unsigned short* Wb  = (unsigned short*)p; p += (size_t)OD * NE * 2;       // 2.1 MB
    unsigned short* Wgb = (unsigned short*)p; p += (size_t)Bn * NGC * NE * 2; // 4.2 MB
    float* Pm    = (float*)p;   p += (size_t)16 * 25600 * 4;          // 1.64 MB
    float* Ps    = (float*)p;   p += (size_t)16 * 25600 * 4;          // 1.64 MB
    float* lse   = (float*)p;   p += (size_t)25600 * 4;               // 0.10 MB
    float* biasg = (float*)p;   p += (size_t)Bn * NGC * 4;            // 16 KB
    float* ast   = (float*)p;   p += (size_t)Bn * Tn * 4;             // 0.10 MB
    float* bst   = (float*)p;   p += (size_t)Bn * Tn * 4;             // 0.10 MB
    float* lossb = (float*)p;   p += 256;

    hipLaunchKernelGGL(cast_hs_kernel, dim3(6400), dim3(256), 0, stream,
                       hs, hsb, 25600 * NE / 8);
    hipLaunchKernelGGL(cast_hs_kernel, dim3(512), dim3(256), 0, stream,
                       W, Wb, OD * NE / 8);
    hipLaunchKernelGGL(gather_kernel, dim3(Bn, NGC), dim3(64), 0, stream,
                       W, bias, ys, Wgb, biasg);
    hipLaunchKernelGGL(gemm_main_kernel, dim3(200, 16), dim3(256), 0, stream,
                       hsb, Wb, bias, Pm, Ps);
    hipLaunchKernelGGL(lse_reduce_kernel, dim3(100), dim3(256), 0, stream,
                       Pm, Ps, lse);
    hipLaunchKernelGGL(gemm_label_kernel, dim3(400, 2), dim3(256), 0, stream,
                       hsb, Wgb, biasg, lse, lpl, lpbk);
    hipLaunchKernelGGL(scan_kernel, dim3(2 * Bn), dim3(256), 0, stream,
                       lpl, lpbk, hlens, ys, ast, bst);
    hipLaunchKernelGGL(loss_kernel, dim3(Bn), dim3(64), 0, stream,
                       hlens, ys, ast, bst, lossb);
    hipLaunchKernelGGL(finalize_kernel, dim3(1), dim3(64), 0, stream, lossb, out);
}

// Round 4
// 1233.581 us; speedup vs baseline: 2.3407x; 1.0006x over previous
//
#include <hip/hip_runtime.h>
#include <math.h>

// BayesianCTC on MI355X — round 15.
// R14 post-mortem: WIN (1712->1234us total, scan 915us) but scan landed at
// the top of the predicted range. Counter evidence: scan VGPR_Count=20, yet
// the alpha/beta waves have 8-12 logically-live prefetch floats + temps.
// The allocator (default occupancy target, ~<=24 VGPR) SANK the emission
// loads to their uses, destroying the distance-4 prefetch -> each step waits
// ~700-900cy on L3. Same mechanism explains R12 (VGPR 28, 3400cyc/step) and
// R13. Occupancy is worthless here (32 blocks on 256 CUs).
// R15: ONE change — __launch_bounds__(256, 1) on scan_kernel to lift the
// VGPR budget so prefetch survives in registers. Everything else identical.
// Predicted: scan VGPR -> 36-64, scan 915 -> 300-500us, total -> 620-820us.

#define Bn    16
#define Tn    1600
#define NE    512
#define OD    2048
#define Un    200
#define Sn    401
#define NLAB  201
#define NGC   256

#define NEGINF (-INFINITY)
#define LSE_SUB_CONST_F (-2000.4586715f)        // -2001 + log(e-1)

typedef short bf8_t  __attribute__((ext_vector_type(8)));
typedef float f32x4  __attribute__((ext_vector_type(4)));

__device__ __forceinline__ unsigned short f2bf(float x) {
    unsigned int u = __float_as_uint(x);
    unsigned int r = (u + 0x7FFFu + ((u >> 16) & 1u)) >> 16;  // RNE
    return (unsigned short)r;
}
__device__ __forceinline__ void lse_merge_v(float& M, float& S, float v) {
    if (v > M) { S = S * __expf(M - v) + 1.f; M = v; }
    else       { S += __expf(v - M); }
}
__device__ __forceinline__ void lse_merge_ms(float& M, float& S, float m2, float s2) {
    if (s2 > 0.f) {
        if (m2 > M) { S = S * __expf(M - m2) + s2; M = m2; }
        else        { S += s2 * __expf(m2 - M); }
    }
}

// ------------------------------------------------------------ casts -------
__global__ __launch_bounds__(256)
void cast_hs_kernel(const float* __restrict__ src, unsigned short* __restrict__ dst, int n8) {
    int i = blockIdx.x * 256 + threadIdx.x;
    if (i >= n8) return;
    const float4* s4 = (const float4*)(src + (size_t)i * 8);
    float4 a = s4[0], b = s4[1];
    uint4 o;
    o.x = f2bf(a.x) | ((unsigned)f2bf(a.y) << 16);
    o.y = f2bf(a.z) | ((unsigned)f2bf(a.w) << 16);
    o.z = f2bf(b.x) | ((unsigned)f2bf(b.y) << 16);
    o.w = f2bf(b.z) | ((unsigned)f2bf(b.w) << 16);
    *(uint4*)(dst + (size_t)i * 8) = o;
}

// --------------------------------------------------------- gather Wg ------
__global__ __launch_bounds__(64)
void gather_kernel(const float* __restrict__ W, const float* __restrict__ bias,
                   const int* __restrict__ ys, unsigned short* __restrict__ Wgb,
                   float* __restrict__ biasg)
{
    const int b = blockIdx.x, j = blockIdx.y, tid = threadIdx.x;
    int col = -1;
    if (j == 0) col = 0;
    else if (j <= Un) { int y = ys[b * Un + j - 1]; col = (y < 0) ? 0 : y; }
    unsigned short* dst = Wgb + ((size_t)b * NGC + j) * NE;
    if (col >= 0) {
        const float* srcc = W + (size_t)col * NE;
        #pragma unroll
        for (int it = 0; it < 8; ++it) dst[tid + it * 64] = f2bf(srcc[tid + it * 64]);
    } else {
        #pragma unroll
        for (int it = 0; it < 8; ++it) dst[tid + it * 64] = 0;
    }
    if (tid == 0) biasg[b * NGC + j] = (col >= 0) ? bias[col] : 0.f;
}

// ------------------------------------------------------- main MFMA GEMM ---
#define KCH  64
#define ASTR 72

__global__ __launch_bounds__(256, 2)
void gemm_main_kernel(const unsigned short* __restrict__ hsb,
                      const unsigned short* __restrict__ Wb,
                      const float* __restrict__ bias,
                      float* __restrict__ Pm, float* __restrict__ Ps)
{
    __shared__ union {
        struct { unsigned short A[128 * ASTR]; unsigned short B[128 * ASTR]; } t;
        struct { float m[128 * 33]; float s[128 * 33]; } r;
    } sh;
    const int tid  = threadIdx.x;
    const int lane = tid & 63, w = tid >> 6;
    const int mw = w & 1, nw = w >> 1;
    const int quad = lane >> 4, lc = lane & 15;
    const int row0 = blockIdx.x * 128;
    const int c0   = blockIdx.y * 128;

    f32x4 acc[4][4];
    #pragma unroll
    for (int mi = 0; mi < 4; ++mi)
        #pragma unroll
        for (int ni = 0; ni < 4; ++ni) acc[mi][ni] = (f32x4)0.f;

    for (int kc = 0; kc < NE / KCH; ++kc) {
        __syncthreads();
        #pragma unroll
        for (int i = 0; i < 4; ++i) {
            int idx = tid + i * 256;
            int r = idx >> 3, c8 = idx & 7;
            *(uint4*)&sh.t.A[r * ASTR + c8 * 8] =
                *(const uint4*)&hsb[(size_t)(row0 + r) * NE + kc * KCH + c8 * 8];
            *(uint4*)&sh.t.B[r * ASTR + c8 * 8] =
                *(const uint4*)&Wb[(size_t)(c0 + r) * NE + kc * KCH + c8 * 8];
        }
        __syncthreads();
        #pragma unroll
        for (int ks = 0; ks < 2; ++ks) {
            bf8_t af[4], bg[4];
            #pragma unroll
            for (int mi = 0; mi < 4; ++mi)
                af[mi] = *(const bf8_t*)&sh.t.A[(mw * 64 + mi * 16 + lc) * ASTR + ks * 32 + quad * 8];
            #pragma unroll
            for (int ni = 0; ni < 4; ++ni)
                bg[ni] = *(const bf8_t*)&sh.t.B[(nw * 64 + ni * 16 + lc) * ASTR + ks * 32 + quad * 8];
            #pragma unroll
            for (int mi = 0; mi < 4; ++mi)
                #pragma unroll
                for (int ni = 0; ni < 4; ++ni)
                    acc[mi][ni] = __builtin_amdgcn_mfma_f32_16x16x32_bf16(af[mi], bg[ni], acc[mi][ni], 0, 0, 0);
        }
    }
    __syncthreads();
    float bcol[4];
    #pragma unroll
    for (int ni = 0; ni < 4; ++ni) bcol[ni] = bias[c0 + nw * 64 + ni * 16 + lc];
    #pragma unroll
    for (int mi = 0; mi < 4; ++mi)
        #pragma unroll
        for (int r = 0; r < 4; ++r) {
            float M = NEGINF, S = 0.f;
            #pragma unroll
            for (int ni = 0; ni < 4; ++ni) lse_merge_v(M, S, acc[mi][ni][r] + bcol[ni]);
            int rl = mw * 64 + mi * 16 + quad * 4 + r;
            sh.r.m[rl * 33 + nw * 16 + lc] = M;
            sh.r.s[rl * 33 + nw * 16 + lc] = S;
        }
    __syncthreads();
    if (tid < 128) {
        float M = NEGINF, S = 0.f;
        #pragma unroll 4
        for (int j = 0; j < 32; ++j) lse_merge_ms(M, S, sh.r.m[tid * 33 + j], sh.r.s[tid * 33 + j]);
        Pm[(size_t)blockIdx.y * 25600 + row0 + tid] = M;
        Ps[(size_t)blockIdx.y * 25600 + row0 + tid] = S;
    }
}

// ------------------------------------------------------------ lse reduce --
__global__ __launch_bounds__(256)
void lse_reduce_kernel(const float* __restrict__ Pm, const float* __restrict__ Ps,
                       float* __restrict__ lse)
{
    int row = blockIdx.x * 256 + threadIdx.x;
    float M = NEGINF, S = 0.f;
    #pragma unroll 4
    for (int nt = 0; nt < 16; ++nt)
        lse_merge_ms(M, S, Pm[(size_t)nt * 25600 + row], Ps[(size_t)nt * 25600 + row]);
    lse[row] = M + logf(S);
}

// ------------------------------------------------------- label MFMA GEMM --
// Output split — lpbk[row] = blank col, lpl[row][u] = label col u (u<200).
__global__ __launch_bounds__(256, 2)
void gemm_label_kernel(const unsigned short* __restrict__ hsb,
                       const unsigned short* __restrict__ Wgb,
                       const float* __restrict__ biasg, const float* __restrict__ lse,
                       float* __restrict__ lpl, float* __restrict__ lpbk)
{
    __shared__ unsigned short shA[64 * ASTR];
    __shared__ unsigned short shB[128 * ASTR];
    const int tid  = threadIdx.x;
    const int lane = tid & 63, w = tid >> 6;
    const int mw = w & 1, nw = w >> 1;
    const int quad = lane >> 4, lc = lane & 15;
    const int b  = blockIdx.x / 25, mt = blockIdx.x % 25;
    const int r0 = b * Tn + mt * 64;
    const int c0 = blockIdx.y * 128;

    f32x4 acc[2][4];
    #pragma unroll
    for (int mi = 0; mi < 2; ++mi)
        #pragma unroll
        for (int ni = 0; ni < 4; ++ni) acc[mi][ni] = (f32x4)0.f;

    const unsigned short* Wgbb = Wgb + (size_t)b * NGC * NE;
    for (int kc = 0; kc < NE / KCH; ++kc) {
        __syncthreads();
        #pragma unroll
        for (int i = 0; i < 2; ++i) {
            int idx = tid + i * 256;
            int r = idx >> 3, c8 = idx & 7;
            *(uint4*)&shA[r * ASTR + c8 * 8] =
                *(const uint4*)&hsb[(size_t)(r0 + r) * NE + kc * KCH + c8 * 8];
        }
        #pragma unroll
        for (int i = 0; i < 4; ++i) {
            int idx = tid + i * 256;
            int r = idx >> 3, c8 = idx & 7;
            *(uint4*)&shB[r * ASTR + c8 * 8] =
                *(const uint4*)&Wgbb[(size_t)(c0 + r) * NE + kc * KCH + c8 * 8];
        }
        __syncthreads();
        #pragma unroll
        for (int ks = 0; ks < 2; ++ks) {
            bf8_t af[2], bg[4];
            #pragma unroll
            for (int mi = 0; mi < 2; ++mi)
                af[mi] = *(const bf8_t*)&shA[(mw * 32 + mi * 16 + lc) * ASTR + ks * 32 + quad * 8];
            #pragma unroll
            for (int ni = 0; ni < 4; ++ni)
                bg[ni] = *(const bf8_t*)&shB[(nw * 64 + ni * 16 + lc) * ASTR + ks * 32 + quad * 8];
            #pragma unroll
            for (int mi = 0; mi < 2; ++mi)
                #pragma unroll
                for (int ni = 0; ni < 4; ++ni)
                    acc[mi][ni] = __builtin_amdgcn_mfma_f32_16x16x32_bf16(af[mi], bg[ni], acc[mi][ni], 0, 0, 0);
        }
    }
    #pragma unroll
    for (int mi = 0; mi < 2; ++mi)
        #pragma unroll
        for (int r = 0; r < 4; ++r) {
            int row = r0 + mw * 32 + mi * 16 + quad * 4 + r;
            float lsv = lse[row];
            #pragma unroll
            for (int ni = 0; ni < 4; ++ni) {
                int col = c0 + nw * 64 + ni * 16 + lc;
                if (col < NLAB) {
                    float v = acc[mi][ni][r] + biasg[b * NGC + col] - lsv;
                    if (col == 0) lpbk[row] = v;
                    else          lpl[(size_t)row * Un + (col - 1)] = v;
                }
            }
        }
}

// ------------------- K2: LDS ping-pong scan, light barrier ----------------
#define IDX(s) ((s) + 2)          // buf index for state s; pads [0,1],[403..407]

__device__ __forceinline__ float lse2f(float a, float b) {
    float mx = fmaxf(a, b);
    if (isinf(mx)) return NEGINF;
    return mx + __logf(__expf(a - mx) + __expf(b - mx));
}
__device__ __forceinline__ float lse3f(float v0, float v1, float v2) {
    float mx = fmaxf(v0, fmaxf(v1, v2));
    if (isinf(mx)) return NEGINF;
    return mx + __logf(__expf(v0 - mx) + __expf(v1 - mx) + __expf(v2 - mx));
}

// LDS-only barrier: ds writes visible, global loads stay in flight (vmcnt
// NOT drained — this is the whole point; __syncthreads would drain it).
#define STEP_BAR() do { \
    asm volatile("s_waitcnt lgkmcnt(0)" ::: "memory"); \
    __builtin_amdgcn_s_barrier(); \
    __builtin_amdgcn_sched_barrier(0); \
} while (0)

__global__ __launch_bounds__(256, 1)   // R15: min-waves/EU=1 -> VGPR budget
void scan_kernel(const float* __restrict__ lpl, const float* __restrict__ lpbk,
                 const int* __restrict__ hlens, const int* __restrict__ ys,
                 float* __restrict__ ast, float* __restrict__ bst)
{
    __shared__ float buf[2][408];
    __shared__ int   sh_olen, sh_hlen;

    const int b    = blockIdx.x & (Bn - 1);
    const int role = blockIdx.x >> 4;
    const int tid  = threadIdx.x;        // thread i owns states 2i, 2i+1

    if (tid == 0) {
        int o = 0;
        for (int u = 0; u < Un; u++) if (ys[b * Un + u] >= 0) o++;
        sh_olen = o;
        sh_hlen = hlens[b];
    }
    for (int idx = tid; idx < 408; idx += 256) {
        buf[0][idx] = NEGINF;
        buf[1][idx] = NEGINF;
    }
    // allow flags in registers (loop-invariant)
    bool a1allow = false;                // allow for odd state s1 (u = tid)
    if (tid >= 1 && tid < Un) {
        int y0 = ys[b * Un + tid - 1]; if (y0 < 0) y0 = 0;
        int y1 = ys[b * Un + tid];     if (y1 < 0) y1 = 0;
        a1allow = (y0 != y1);
    }
    bool a2allow = false;                // allow for odd state s1+2 (u = tid+1)
    if (tid + 1 >= 1 && tid + 1 < Un) {
        int y0 = ys[b * Un + tid];     if (y0 < 0) y0 = 0;
        int y1 = ys[b * Un + tid + 1]; if (y1 < 0) y1 = 0;
        a2allow = (y0 != y1);
    }
    __syncthreads();

    const float* lplb = lpl + (size_t)b * Tn * Un;
    const float* lpbb = lpbk + (size_t)b * Tn;
    const int s0 = 2 * tid, s1 = 2 * tid + 1;
    const bool v0ok = (s0 < Sn);         // tid <= 200
    const bool v1ok = (s1 < Sn);         // tid < 200
    const int  olen = sh_olen, hlen = sh_hlen;
    const int  ustar = olen - 1;

    if (role == 0) {
        // ------------------------- alpha -------------------------
        float* as = ast + (size_t)b * Tn;
        if (tid == 0) { buf[0][IDX(0)] = lpbb[0]; buf[0][IDX(1)] = lplb[0]; }
        if (tid == ustar) as[0] = (tid == 0) ? lplb[0] : NEGINF;
        __syncthreads();

        #define ASTEP(T, EB, EO) do { \
            const float* cur = buf[((T) - 1) & 1]; \
            float* nxt = buf[(T) & 1]; \
            if (v0ok) { \
                float c1 = cur[IDX(s0) - 1]; \
                float c2 = cur[IDX(s0)], c3 = cur[IDX(s1)]; \
                float nv0 = lse2f(c2, c1); \
                if (!isinf(nv0)) nv0 += (EB); \
                nxt[IDX(s0)] = nv0; \
                if (v1ok) { \
                    float a1v2 = a1allow ? c1 : NEGINF; \
                    float nv1 = lse3f(c3, c2, a1v2); \
                    if (!isinf(nv1)) nv1 += (EO); \
                    nxt[IDX(s1)] = nv1; \
                    if (tid == ustar) as[T] = nv1; \
                } \
            } \
            STEP_BAR(); \
        } while (0)

        // depth-4 prefetch: sets A..D hold emission rows t..t+3
        float ebA = lpbb[1], ebB = lpbb[2], ebC = lpbb[3], ebD = lpbb[4];
        float eoA = (tid < Un) ? lplb[(size_t)1 * Un + tid] : 0.f;
        float eoB = (tid < Un) ? lplb[(size_t)2 * Un + tid] : 0.f;
        float eoC = (tid < Un) ? lplb[(size_t)3 * Un + tid] : 0.f;
        float eoD = (tid < Un) ? lplb[(size_t)4 * Un + tid] : 0.f;
        int t = 1;
        for (; t + 3 < Tn; t += 4) {       // t = 1..1593, covers steps to 1596
            int rA = t + 4; if (rA > Tn - 1) rA = Tn - 1;
            float nbA = lpbb[rA];
            float noA = (tid < Un) ? lplb[(size_t)rA * Un + tid] : 0.f;
            ASTEP(t, ebA, eoA); ebA = nbA; eoA = noA;

            int rB = t + 5; if (rB > Tn - 1) rB = Tn - 1;
            float nbB = lpbb[rB];
            float noB = (tid < Un) ? lplb[(size_t)rB * Un + tid] : 0.f;
            ASTEP(t + 1, ebB, eoB); ebB = nbB; eoB = noB;

            int rC = t + 6; if (rC > Tn - 1) rC = Tn - 1;
            float nbC = lpbb[rC];
            float noC = (tid < Un) ? lplb[(size_t)rC * Un + tid] : 0.f;
            ASTEP(t + 2, ebC, eoC); ebC = nbC; eoC = noC;

            int rD = t + 7; if (rD > Tn - 1) rD = Tn - 1;
            float nbD = lpbb[rD];
            float noD = (tid < Un) ? lplb[(size_t)rD * Un + tid] : 0.f;
            ASTEP(t + 3, ebD, eoD); ebD = nbD; eoD = noD;
        }
        // tail: t = 1597, 1598, 1599 (sets A,B,C already hold those rows)
        if (t < Tn)     ASTEP(t,     ebA, eoA);
        if (t + 1 < Tn) ASTEP(t + 1, ebB, eoB);
        if (t + 2 < Tn) ASTEP(t + 2, ebC, eoC);
        #undef ASTEP
    } else {
        // ------------------ beta + in-scan beta_prime ------------------
        float* bs = bst + (size_t)b * Tn;
        __syncthreads();

        #define BSTEP(T, EB, E0, E1) do { \
            const int it = (Tn - 1 - (T)) & 1; \
            const float* cur = buf[it]; \
            float* nxt = buf[it ^ 1]; \
            if (v0ok) { \
                float c0 = cur[IDX(s0)],     c1 = cur[IDX(s0) + 1]; \
                float c2 = cur[IDX(s0) + 2], c3 = cur[IDX(s0) + 3]; \
                float g0e = (EB) + c0; \
                float g1e = (E0) + c1; \
                float nv0 = lse2f(g0e, g1e); \
                float g0o = (E0) + c1; \
                float g1o = (EB) + c2; \
                float g2o = a2allow ? ((E1) + c3) : NEGINF; \
                float mh = fmaxf(g1o, g2o); \
                float h = NEGINF; \
                if (!isinf(mh)) \
                    h = mh + __logf(__expf(g1o - mh) + __expf(g2o - mh)); \
                float nv1 = v1ok ? lse3f(g0o, g1o, g2o) : NEGINF; \
                if ((T) == hlen - 1) { \
                    nv0 = (s0 == 2 * olen || s0 == 2 * olen - 1) ? 0.f : NEGINF; \
                    nv1 = (s1 == 2 * olen || s1 == 2 * olen - 1) ? 0.f : NEGINF; \
                } \
                nxt[IDX(s0)] = nv0; \
                if (v1ok) { \
                    nxt[IDX(s1)] = nv1; \
                    if (tid == ustar) { \
                        float bp; \
                        if ((T) >= hlen)          bp = NEGINF; \
                        else if ((T) == hlen - 1) bp = 0.f; /* tid==olen-1 */ \
                        else if (isinf(g0o))      bp = h; \
                        else if (isinf(h))        bp = LSE_SUB_CONST_F; \
                        else { \
                            float sumlog = h - g0o; \
                            int k = (int)((__float_as_uint(fabsf(g0o)) >> 23) & 0xFF) - 127 - 53; \
                            if (k < -53) k = -53; \
                            bp = (sumlog > 709.7827f || sumlog < 0.69314718f * (float)k) \
                                 ? LSE_SUB_CONST_F : h; \
                        } \
                        bs[T] = bp; \
                    } \
                } \
            } \
            STEP_BAR(); \
        } while (0)

        // step T uses emission row min(T+1, Tn-1).
        // prologue: steps 1599,1598,1597,1596 -> rows 1599,1599,1598,1597.
        float ebA = lpbb[Tn - 1];
        float e0A = (tid < Un)     ? lplb[(size_t)(Tn - 1) * Un + tid]     : 0.f;
        float e1A = (tid + 1 < Un) ? lplb[(size_t)(Tn - 1) * Un + tid + 1] : 0.f;
        float ebB = ebA, e0B = e0A, e1B = e1A;
        float ebC = lpbb[Tn - 2];
        float e0C = (tid < Un)     ? lplb[(size_t)(Tn - 2) * Un + tid]     : 0.f;
        float e1C = (tid + 1 < Un) ? lplb[(size_t)(Tn - 2) * Un + tid + 1] : 0.f;
        float ebD = lpbb[Tn - 3];
        float e0D = (tid < Un)     ? lplb[(size_t)(Tn - 3) * Un + tid]     : 0.f;
        float e1D = (tid + 1 < Un) ? lplb[(size_t)(Tn - 3) * Un + tid + 1] : 0.f;
        for (int t = Tn - 1; t > 0; t -= 4) {   // 400 iters, steps t..t-3
            int rA = t - 3; if (rA < 0) rA = 0;     // row for step t-4
            float nbA = lpbb[rA];
            float n0A = (tid < Un)     ? lplb[(size_t)rA * Un + tid]     : 0.f;
            float n1A = (tid + 1 < Un) ? lplb[(size_t)rA * Un + tid + 1] : 0.f;
            BSTEP(t, ebA, e0A, e1A); ebA = nbA; e0A = n0A; e1A = n1A;

            int rB = t - 4; if (rB < 0) rB = 0;     // row for step t-5
            float nbB = lpbb[rB];
            float n0B = (tid < Un)     ? lplb[(size_t)rB * Un + tid]     : 0.f;
            float n1B = (tid + 1 < Un) ? lplb[(size_t)rB * Un + tid + 1] : 0.f;
            BSTEP(t - 1, ebB, e0B, e1B); ebB = nbB; e0B = n0B; e1B = n1B;

            int rC = t - 5; if (rC < 0) rC = 0;     // row for step t-6
            float nbC = lpbb[rC];
            float n0C = (tid < Un)     ? lplb[(size_t)rC * Un + tid]     : 0.f;
            float n1C = (tid + 1 < Un) ? lplb[(size_t)rC * Un + tid + 1] : 0.f;
            BSTEP(t - 2, ebC, e0C, e1C); ebC = nbC; e0C = n0C; e1C = n1C;

            int rD = t - 6; if (rD < 0) rD = 0;     // row for step t-7
            float nbD = lpbb[rD];
            float n0D = (tid < Un)     ? lplb[(size_t)rD * Un + tid]     : 0.f;
            float n1D = (tid + 1 < Un) ? lplb[(size_t)rD * Un + tid + 1] : 0.f;
            BSTEP(t - 3, ebD, e0D, e1D); ebD = nbD; e0D = n0D; e1D = n1D;
        }
        #undef BSTEP
    }
}

// --------------------- K3: loss at u* only --------------------------------
#define TCH 8
#define TPC (Tn / TCH)

__global__ __launch_bounds__(64)
void loss_kernel(const int* __restrict__ hlens, const int* __restrict__ ys,
                 const float* __restrict__ ast, const float* __restrict__ bst,
                 float* __restrict__ lossb)
{
    const int b = blockIdx.x, tid = threadIdx.x;
    __shared__ float sm[TCH], ss[TCH];
    __shared__ int sh_olen;
    if (tid == 0) {
        int o = 0;
        for (int u = 0; u < Un; u++) if (ys[b * Un + u] >= 0) o++;
        sh_olen = o;
    }
    __syncthreads();
    const int hlen = hlens[b];
    const float risk_c = 0.1f / (float)hlen;
    if (tid < TCH) {
        float m = NEGINF, s = 0.f;
        const float* as = ast + (size_t)b * Tn;
        const float* bs = bst + (size_t)b * Tn;
        const int t0 = tid * TPC, t1 = t0 + TPC;
        for (int t = t0; t < t1; ++t) {
            float v = as[t] + bs[t] + (float)(t + 1) * risk_c;
            if (!isinf(v)) lse_merge_v(m, s, v);
        }
        sm[tid] = m; ss[tid] = s;
    }
    __syncthreads();
    if (tid == 0) {
        float M = NEGINF, S = 0.f;
        #pragma unroll
        for (int c = 0; c < TCH; ++c) lse_merge_ms(M, S, sm[c], ss[c]);
        float lf = (S == 0.f) ? NEGINF : M + __logf(S);
        if (hlen < sh_olen) lf = 0.f;
        lossb[b] = lf;
    }
}

// ---------------------------------------------------------------- K4 ------
__global__ void finalize_kernel(const float* __restrict__ lossb, float* __restrict__ out) {
    if (threadIdx.x == 0 && blockIdx.x == 0) {
        float ssum = 0.f;
        for (int i = 0; i < Bn; i++) ssum += lossb[i];
        out[0] = -ssum / (float)Bn;
    }
}

// ------------------------------------------------------------- launch -----
extern "C" void kernel_launch(void* const* d_in, const int* in_sizes, int n_in,
                              void* d_out, int out_size, void* d_ws, size_t ws_size,
                              hipStream_t stream) {
    const float* hs    = (const float*)d_in[0];
    const float* W     = (const float*)d_in[1];
    const float* bias  = (const float*)d_in[2];
    const int*   hlens = (const int*)d_in[3];
    const int*   ys    = (const int*)d_in[4];
    float* out = (float*)d_out;

    // ---- workspace (~57 MB) ----
    char* p = (char*)d_ws;
    float* lpl    = (float*)p;  p += (size_t)25600 * Un * 4;          // 20.48 MB
    float* lpbk   = (float*)p;  p += (size_t)25600 * 4;               // 0.10 MB
    unsigned short* hsb = (unsigned short*)p; p += (size_t)25600 * NE * 2;    // 26.2 MB
    unsigned short* Wb  = (unsigned short*)p; p += (size_t)OD * NE * 2;       // 2.1 MB
    unsigned short* Wgb = (unsigned short*)p; p += (size_t)Bn * NGC * NE * 2; // 4.2 MB
    float* Pm    = (float*)p;   p += (size_t)16 * 25600 * 4;          // 1.64 MB
    float* Ps    = (float*)p;   p += (size_t)16 * 25600 * 4;          // 1.64 MB
    float* lse   = (float*)p;   p += (size_t)25600 * 4;               // 0.10 MB
    float* biasg = (float*)p;   p += (size_t)Bn * NGC * 4;            // 16 KB
    float* ast   = (float*)p;   p += (size_t)Bn * Tn * 4;             // 0.10 MB
    float* bst   = (float*)p;   p += (size_t)Bn * Tn * 4;             // 0.10 MB
    float* lossb = (float*)p;   p += 256;

    hipLaunchKernelGGL(cast_hs_kernel, dim3(6400), dim3(256), 0, stream,
                       hs, hsb, 25600 * NE / 8);
    hipLaunchKernelGGL(cast_hs_kernel, dim3(512), dim3(256), 0, stream,
                       W, Wb, OD * NE / 8);
    hipLaunchKernelGGL(gather_kernel, dim3(Bn, NGC), dim3(64), 0, stream,
                       W, bias, ys, Wgb, biasg);
    hipLaunchKernelGGL(gemm_main_kernel, dim3(200, 16), dim3(256), 0, stream,
                       hsb, Wb, bias, Pm, Ps);
    hipLaunchKernelGGL(lse_reduce_kernel, dim3(100), dim3(256), 0, stream,
                       Pm, Ps, lse);
    hipLaunchKernelGGL(gemm_label_kernel, dim3(400, 2), dim3(256), 0, stream,
                       hsb, Wgb, biasg, lse, lpl, lpbk);
    hipLaunchKernelGGL(scan_kernel, dim3(2 * Bn), dim3(256), 0, stream,
                       lpl, lpbk, hlens, ys, ast, bst);
    hipLaunchKernelGGL(loss_kernel, dim3(Bn), dim3(64), 0, stream,
                       hlens, ys, ast, bst, lossb);
    hipLaunchKernelGGL(finalize_kernel, dim3(1), dim3(64), 0, stream, lossb, out);
}